// Round 10
// baseline (276.402 us; speedup 1.0000x reference)
//
#include <hip/hip_runtime.h>

#define OUT_F 11008
#define IN_F  4096
#define NBATCH 8
#define RB 16                    // rows per block
#define BLOCK 256
#define COLS 2048                // cols per block (chunk)
#define CHUNKS (IN_F / COLS)     // 2
#define GPC (COLS / 128)         // 16 groups per row within a chunk
#define ITERS 8                  // per wave: 8 x (4 rows x 256 cols) = 16r x 512c
#define DEPTH 3                  // idx pipeline stages (8 KB steady in flight/wave)

__device__ __forceinline__ unsigned short bf16_rne(float f) {
    unsigned int b = __float_as_uint(f);
    b += 0x7FFFu + ((b >> 16) & 1u);
    return (unsigned short)(b >> 16);
}
__device__ __forceinline__ float bf16_up(unsigned short u) {
    return __uint_as_float(((unsigned int)u) << 16);
}

// Rolling-pipeline streaming kernel: steady-state VMEM queue = pure idx
// stream, 3 stages deep (waiting on the oldest stage leaves 8 younger loads
// in flight -> continuous HBM issue; R3-R9 all drained to zero each phase,
// capping at ~2.5 TB/s). x (bf16) and lut (f32) live in LDS (lgkmcnt domain).
__global__ __launch_bounds__(BLOCK) void pal_linear_kernel(
    const float* __restrict__ x,        // [8, 4096]
    const int*   __restrict__ widx,     // [11008*4096] in [0,16)
    const float* __restrict__ lut,      // [352256, 16] f32 on device
    const float* __restrict__ bias,     // [11008]
    float* __restrict__ out)            // [8, 11008], zeroed by memsetAsync
{
    __shared__ unsigned short xS[NBATCH * COLS];   // 32 KB bf16
    __shared__ float lutS[RB * GPC * 16];          // 16 KB

    const int tid   = threadIdx.x;
    const int lane  = tid & 63;
    const int wave  = tid >> 6;
    const int rowG  = blockIdx.x >> 1;             // CHUNKS = 2
    const int chunk = blockIdx.x & 1;
    const int o0    = rowG * RB;
    const int c0    = chunk * COLS;
    const int wcol  = wave * 512;                  // wave's 512-col window

    // ---- 1) prologue idx loads (stages 0..2) FIRST: oldest in vmcnt queue ----
    int4 buf[DEPTH][4];
#pragma unroll
    for (int s = 0; s < DEPTH; ++s) {
        const int rs = (s & 3) * 4, cs = (s >> 2) * 256;
#pragma unroll
        for (int j = 0; j < 4; ++j)
            buf[s][j] = *reinterpret_cast<const int4*>(
                widx + (size_t)(o0 + rs + j) * IN_F + c0 + wcol + cs + 4 * lane);
    }

    // ---- 2) stage x chunk as bf16 (RNE): 8 x 2048 -> 32 KB ----
#pragma unroll
    for (int i = 0; i < 16; ++i) {
        const int j  = tid + i * BLOCK;            // float4 id 0..4095
        const int m  = j >> 9;
        const int cc = (j & 511) * 4;
        const float4 v = *reinterpret_cast<const float4*>(x + m * IN_F + c0 + cc);
        ushort4 p;
        p.x = bf16_rne(v.x); p.y = bf16_rne(v.y);
        p.z = bf16_rne(v.z); p.w = bf16_rne(v.w);
        *reinterpret_cast<ushort4*>(xS + m * COLS + cc) = p;
    }

    // ---- 3) stage lut slice: 16 rows x 16 groups x 16 entries (f32) ----
#pragma unroll
    for (int i = 0; i < 4; ++i) {
        const int j  = tid + i * BLOCK;            // float4 id 0..1023
        const int r  = j >> 6;
        const int w4 = (j & 63) * 4;
        *reinterpret_cast<float4*>(lutS + r * (GPC * 16) + w4) =
            *reinterpret_cast<const float4*>(
                lut + (size_t)(o0 + r) * 512 + chunk * 256 + w4);
    }

    __syncthreads();

    float acc[RB][NBATCH];
#pragma unroll
    for (int r = 0; r < RB; ++r)
#pragma unroll
        for (int m = 0; m < NBATCH; ++m) acc[r][m] = 0.0f;

    // ---- 4) steady-state loop: consume oldest stage, refill, FMA ----
#pragma unroll
    for (int it = 0; it < ITERS; ++it) {
        const int s  = it % DEPTH;
        const int rs = (it & 3) * 4, cs = (it >> 2) * 256;
        const int cl = wcol + cs + 4 * lane;       // col within chunk, 0..2047
        const int g  = cl >> 7;                    // per-lane group within chunk

        // gathers (consume buf[s]; compiler waits only this stage's vmcnt)
        float w[4][4];
#pragma unroll
        for (int j = 0; j < 4; ++j) {
            const float* lr = lutS + (rs + j) * (GPC * 16) + g * 16;
            w[j][0] = lr[buf[s][j].x];
            w[j][1] = lr[buf[s][j].y];
            w[j][2] = lr[buf[s][j].z];
            w[j][3] = lr[buf[s][j].w];
        }

        // refill stage s (issues before the FMAs; rides through them)
        if (it + DEPTH < ITERS) {
            const int rs2 = ((it + DEPTH) & 3) * 4, cs2 = ((it + DEPTH) >> 2) * 256;
#pragma unroll
            for (int j = 0; j < 4; ++j)
                buf[s][j] = *reinterpret_cast<const int4*>(
                    widx + (size_t)(o0 + rs2 + j) * IN_F + c0 + wcol + cs2 + 4 * lane);
        }

        // FMAs: x from LDS (b64, 2-way bank = free), all static indexing
#pragma unroll
        for (int m = 0; m < NBATCH; ++m) {
            const ushort4 xb = *reinterpret_cast<const ushort4*>(xS + m * COLS + cl);
            const float x0 = bf16_up(xb.x), x1 = bf16_up(xb.y);
            const float x2 = bf16_up(xb.z), x3 = bf16_up(xb.w);
#pragma unroll
            for (int j = 0; j < 4; ++j) {
                float a = acc[rs + j][m];
                a = fmaf(w[j][0], x0, a);
                a = fmaf(w[j][1], x1, a);
                a = fmaf(w[j][2], x2, a);
                a = fmaf(w[j][3], x3, a);
                acc[rs + j][m] = a;
            }
        }
    }

    // ---- 5) epilogue: per 4-row group, packed wave reduce + direct atomics ----
#pragma unroll
    for (int gq = 0; gq < 4; ++gq) {
        float f[4][NBATCH];
#pragma unroll
        for (int r = 0; r < 4; ++r)
#pragma unroll
            for (int m = 0; m < NBATCH; ++m) {
                const float a = acc[gq * 4 + r][m];
                f[r][m] = a + __shfl_xor(a, 32, 64);
            }
        float e[16];
#pragma unroll
        for (int r = 0; r < 4; ++r)
#pragma unroll
            for (int q = 0; q < 4; ++q)
                e[r * 4 + q] = (lane < 32) ? f[r][2 * q] : f[r][2 * q + 1];
#pragma unroll
        for (int off = 16; off >= 1; off >>= 1)
#pragma unroll
            for (int p = 0; p < 16; ++p)
                e[p] += __shfl_xor(e[p], off, 64);

        const int p = lane & 15;
        float v = 0.0f;
#pragma unroll
        for (int pp = 0; pp < 16; ++pp)
            if (p == pp) v = e[pp];                // static cndmask chain

        const bool lo = (lane < 16);
        const bool hi = (lane >= 32) && (lane < 48);
        if (lo || hi) {
            const int r   = p >> 2;
            const int m   = 2 * (p & 3) + (lo ? 0 : 1);
            const int row = o0 + gq * 4 + r;
            if (chunk == 0 && wave == 0) v += bias[row];   // bias exactly once
            atomicAdd(out + (size_t)m * OUT_F + row, v);
        }
    }
}

extern "C" void kernel_launch(void* const* d_in, const int* in_sizes, int n_in,
                              void* d_out, int out_size, void* d_ws, size_t ws_size,
                              hipStream_t stream) {
    const float* x    = (const float*)d_in[0];
    const int*   widx = (const int*)d_in[1];
    const float* lut  = (const float*)d_in[2];
    const float* bias = (const float*)d_in[3];
    float* out = (float*)d_out;

    hipMemsetAsync(out, 0, (size_t)out_size * sizeof(float), stream);
    pal_linear_kernel<<<(OUT_F / RB) * CHUNKS, BLOCK, 0, stream>>>(
        x, widx, lut, bias, out);
}